// Round 11
// baseline (90.052 us; speedup 1.0000x reference)
//
#include <hip/hip_runtime.h>
#include <hip/hip_bf16.h>

typedef short s4 __attribute__((ext_vector_type(4)));
typedef short s8 __attribute__((ext_vector_type(8)));
typedef float f4 __attribute__((ext_vector_type(4)));

#define MFMA16(a, b, c) __builtin_amdgcn_mfma_f32_16x16x16bf16_1k(a, b, c, 0, 0, 0)

__device__ __forceinline__ short f2bf(float f) {
    union { float f; unsigned u; } v; v.f = f;
    unsigned r = v.u + 0x7fffu + ((v.u >> 16) & 1u);   // RNE
    return (short)(r >> 16);
}

// ---------------------------------------------------------------------------
// Kernel 1: projections — identical to round 8 (best timed: ~47 us warm).
// V (which==2) stored as transposed 64-key tiles vpT[b][tile][d][key].
// ---------------------------------------------------------------------------
struct ProjArgs {
    const float* X[3];
    const float* W[3];
    const float* b[3];
    unsigned short* O[3];
};

__global__ __launch_bounds__(256) void proj_kernel(ProjArgs args) {
    __shared__ short lA[64][68];   // [row][k]
    __shared__ short lW[64][68];   // [k][n]

    const int t  = threadIdx.x;
    const int wv = t >> 6, ln = t & 63, lg = ln >> 4, lr = ln & 15;
    const int which = blockIdx.y;

    const float* X = args.X[which] + (size_t)blockIdx.x * 64 * 1024;
    const float* W = args.W[which];

    f4 acc[4] = {f4{0,0,0,0}, f4{0,0,0,0}, f4{0,0,0,0}, f4{0,0,0,0}};

    for (int kk = 0; kk < 1024; kk += 64) {
        #pragma unroll
        for (int i = 0; i < 4; ++i) {
            int f  = t + i * 256;
            int r  = f >> 4;
            int c4 = f & 15;
            f4 a = *(const f4*)(X + (size_t)r * 1024 + kk + c4 * 4);
            f4 w = *(const f4*)(W + (size_t)(kk + r) * 64 + c4 * 4);
            s4 ab; ab[0]=f2bf(a[0]); ab[1]=f2bf(a[1]); ab[2]=f2bf(a[2]); ab[3]=f2bf(a[3]);
            s4 wb; wb[0]=f2bf(w[0]); wb[1]=f2bf(w[1]); wb[2]=f2bf(w[2]); wb[3]=f2bf(w[3]);
            *(s4*)&lA[r][c4 * 4] = ab;
            *(s4*)&lW[r][c4 * 4] = wb;
        }
        __syncthreads();

        #pragma unroll
        for (int ks = 0; ks < 4; ++ks) {
            s4 af = *(const s4*)&lA[wv * 16 + lr][ks * 16 + 4 * lg];
            #pragma unroll
            for (int nf = 0; nf < 4; ++nf) {
                s4 bf;
                #pragma unroll
                for (int e = 0; e < 4; ++e)
                    bf[e] = lW[ks * 16 + 4 * lg + e][nf * 16 + lr];
                acc[nf] = MFMA16(af, bf, acc[nf]);
            }
        }
        __syncthreads();
    }

    const float* bias = args.b[which];
    unsigned short* O = args.O[which];
    #pragma unroll
    for (int nf = 0; nf < 4; ++nf) {
        float bs = bias[nf * 16 + lr];
        int col = nf * 16 + lr;
        #pragma unroll
        for (int e = 0; e < 4; ++e) {
            int r = wv * 16 + 4 * lg + e;
            int grow = blockIdx.x * 64 + r;
            unsigned short val = (unsigned short)f2bf(acc[nf][e] + bs);
            if (which == 2) {
                size_t idx = (size_t)(grow >> 11) * 131072
                           + (size_t)((grow & 2047) >> 6) * 4096
                           + (size_t)col * 64 + (grow & 63);
                O[idx] = val;
            } else {
                O[(size_t)grow * 64 + col] = val;
            }
        }
    }
}

// ---------------------------------------------------------------------------
// Kernel 2 v11: causal flash attention, KEY-SLICED waves.
// 8 waves: wave w owns kv-tile-sub (w>>2) and 16-key slice s = w&3.
// Per iter: 2 kv-tiles consumed; per wave only 4 K-frag + 4 V-frag b64 LDS
// reads (reused across 4 q-frags; Q in registers all kernel). Softmax in
// exp2 units with defer-max (THR=8). 8-way merge via LDS at end.
// grid (32, 8), block 512. LDS 70-stride (~1.2-way conflicts).
// ---------------------------------------------------------------------------
__global__ __launch_bounds__(512) void attn_kernel(const unsigned short* __restrict__ qp,
                                                   const unsigned short* __restrict__ kp,
                                                   const unsigned short* __restrict__ vpT,
                                                   float* __restrict__ out) {
    __shared__ short lK[2][2][64][70];   // [buf][tileSub][key][d]
    __shared__ short lV[2][2][64][70];   // [buf][tileSub][d][key]

    const int t    = threadIdx.x;
    const int w    = t >> 6, ln = t & 63, lg = ln >> 4, lr = ln & 15;
    const int sub  = w >> 2, sl = w & 3;          // compute: tile-sub, key-slice
    const int b = blockIdx.y, qt = blockIdx.x;
    const int niter = (qt >> 1) + 1;

    // staging role: group g = t>>7: 0=K sub0, 1=K sub1, 2=V sub0, 3=V sub1
    const int g = t >> 7, gi = t & 127, gsub = g & 1;
    const bool isV = g >= 2;
    const unsigned short* tb = (isV ? vpT : kp) + (size_t)b * 131072;

    // Q fragments in registers for the whole kernel: qf_r[qf][ks]
    const unsigned short* qpb = qp + (size_t)b * 131072;
    s4 qf_r[4][4];
    #pragma unroll
    for (int qf = 0; qf < 4; ++qf)
        #pragma unroll
        for (int ks = 0; ks < 4; ++ks)
            qf_r[qf][ks] = *(const s4*)(qpb + (size_t)(qt * 64 + 16 * qf + lr) * 64
                                            + 16 * ks + 4 * lg);

    f4 accO[4][4];                                 // [df][qf]
    #pragma unroll
    for (int df = 0; df < 4; ++df)
        #pragma unroll
        for (int qf = 0; qf < 4; ++qf) accO[df][qf] = f4{0,0,0,0};
    float m[4] = {-3e38f, -3e38f, -3e38f, -3e38f};
    float l[4] = {0.f, 0.f, 0.f, 0.f};

    const float C = 0.125f * 1.44269504f;          // scale * log2(e): exp2 units

    // prologue: prefetch iter-0 tile for this staging group
    s8 stg[4];
    {
        const unsigned short* p = tb + (size_t)gsub * 4096;
        #pragma unroll
        for (int i = 0; i < 4; ++i)
            stg[i] = *(const s8*)(p + (gi + 128 * i) * 8);
    }

    int buf = 0;
    for (int j = 0; j < niter; ++j) {
        // write staged regs -> LDS[buf][gsub]
        {
            short (*dst)[70] = isV ? lV[buf][gsub] : lK[buf][gsub];
            #pragma unroll
            for (int i = 0; i < 4; ++i) {
                int s = gi + 128 * i;
                *(s8*)&dst[s >> 3][(s & 7) * 8] = stg[i];
            }
        }
        __syncthreads();

        if (j + 1 < niter) {
            const unsigned short* p = tb + (size_t)(2 * (j + 1) + gsub) * 4096;
            #pragma unroll
            for (int i = 0; i < 4; ++i)
                stg[i] = *(const s8*)(p + (gi + 128 * i) * 8);
        }

        const int myTile = 2 * j + sub;
        if (myTile <= qt) {
            // K-frags: 4 b64, reused across all q-frags
            s4 kfr[4];
            #pragma unroll
            for (int ks = 0; ks < 4; ++ks)
                kfr[ks] = *(const s4*)&lK[buf][sub][16 * sl + lr][16 * ks + 4 * lg];

            // S^T = K_slice . Q^T : st[qf] with key = 4lg+e, q = 16qf+lr
            f4 st[4];
            #pragma unroll
            for (int qf = 0; qf < 4; ++qf) {
                f4 a = f4{0,0,0,0};
                #pragma unroll
                for (int ks = 0; ks < 4; ++ks)
                    a = MFMA16(kfr[ks], qf_r[qf][ks], a);
                st[qf] = a;
            }

            // scale to exp2 units + causal mask
            const bool diag = (myTile == qt);
            const int kbase = myTile * 64 + 16 * sl + 4 * lg;
            float pmax[4];
            #pragma unroll
            for (int qf = 0; qf < 4; ++qf) {
                f4 s2;
                #pragma unroll
                for (int e = 0; e < 4; ++e) {
                    float s = st[qf][e] * C;
                    if (diag && (kbase + e > qt * 64 + 16 * qf + lr)) s = -1e30f;
                    s2[e] = s;
                }
                st[qf] = s2;
                float mx = fmaxf(fmaxf(s2[0], s2[1]), fmaxf(s2[2], s2[3]));
                mx = fmaxf(mx, __shfl_xor(mx, 16));
                mx = fmaxf(mx, __shfl_xor(mx, 32));
                pmax[qf] = mx;
            }

            // defer-max: rescale only when growth > 8 (in log2 units)
            float grow = fmaxf(fmaxf(pmax[0] - m[0], pmax[1] - m[1]),
                               fmaxf(pmax[2] - m[2], pmax[3] - m[3]));
            if (!__all(grow <= 8.0f)) {
                #pragma unroll
                for (int qf = 0; qf < 4; ++qf) {
                    float mn = fmaxf(m[qf], pmax[qf]);
                    float sc = __builtin_amdgcn_exp2f(m[qf] - mn);
                    l[qf] *= sc;
                    m[qf] = mn;
                    #pragma unroll
                    for (int df = 0; df < 4; ++df) accO[df][qf] *= sc;
                }
            }

            // P = exp2(s2 - m), psum, bf16 convert (P bounded by 2^8)
            s4 pb[4];
            #pragma unroll
            for (int qf = 0; qf < 4; ++qf) {
                f4 p;
                #pragma unroll
                for (int e = 0; e < 4; ++e)
                    p[e] = __builtin_amdgcn_exp2f(st[qf][e] - m[qf]);
                float ps = (p[0] + p[1]) + (p[2] + p[3]);
                ps += __shfl_xor(ps, 16);
                ps += __shfl_xor(ps, 32);
                l[qf] += ps;
                s4 pc; pc[0]=f2bf(p[0]); pc[1]=f2bf(p[1]); pc[2]=f2bf(p[2]); pc[3]=f2bf(p[3]);
                pb[qf] = pc;
            }

            // PV: O^T[d][q] += V^T_slice . P^T  (V-frags reused across q-frags)
            #pragma unroll
            for (int df = 0; df < 4; ++df) {
                s4 vf = *(const s4*)&lV[buf][sub][16 * df + lr][16 * sl + 4 * lg];
                #pragma unroll
                for (int qf = 0; qf < 4; ++qf)
                    accO[df][qf] = MFMA16(vf, pb[qf], accO[df][qf]);
            }
        }
        buf ^= 1;
    }

    // ---- 8-way merge via LDS (aliases lK) ----
    __syncthreads();
    float* arena = (float*)&lK[0][0][0][0];
    float* ml   = arena;              // [8 waves][4 qf][16 lr][2] = 1024 floats
    float* Linv = arena + 1024;       // [64]
    float* Oacc = arena + 1152;       // [64 d][66] = 4224 floats

    if (lg == 0) {
        #pragma unroll
        for (int qf = 0; qf < 4; ++qf) {
            int idx = ((w * 4 + qf) * 16 + lr) * 2;
            ml[idx] = m[qf];
            ml[idx + 1] = l[qf];
        }
    }
    __syncthreads();

    float scOwn[4];
    {
        #pragma unroll
        for (int qf = 0; qf < 4; ++qf) {
            float M = -3e38f;
            #pragma unroll
            for (int w2 = 0; w2 < 8; ++w2)
                M = fmaxf(M, ml[((w2 * 4 + qf) * 16 + lr) * 2]);
            float L = 0.f;
            #pragma unroll
            for (int w2 = 0; w2 < 8; ++w2) {
                int idx = ((w2 * 4 + qf) * 16 + lr) * 2;
                L += __builtin_amdgcn_exp2f(ml[idx] - M) * ml[idx + 1];
            }
            scOwn[qf] = __builtin_amdgcn_exp2f(m[qf] - M);
            if (w == 0 && lg == 0) Linv[16 * qf + lr] = 1.f / L;
        }
    }
    __syncthreads();

    // sequential scaled accumulation of O partials
    for (int step = 0; step < 8; ++step) {
        if (w == step) {
            #pragma unroll
            for (int df = 0; df < 4; ++df)
                #pragma unroll
                for (int qf = 0; qf < 4; ++qf)
                    #pragma unroll
                    for (int e = 0; e < 4; ++e) {
                        int idx = (16 * df + 4 * lg + e) * 66 + 16 * qf + lr;
                        float v = scOwn[qf] * accO[df][qf][e];
                        if (step == 0) Oacc[idx] = v; else Oacc[idx] += v;
                    }
        }
        __syncthreads();
    }

    // final write: thread t covers out row (qt*64 + (t>>3)), d = (t&7)*8..+7
    {
        int row = t >> 3, c8 = t & 7;
        float li = Linv[row];
        float* ob = out + ((size_t)b * 2048 + qt * 64 + row) * 64 + c8 * 8;
        f4 o0, o1;
        #pragma unroll
        for (int i = 0; i < 4; ++i) o0[i] = Oacc[(c8 * 8 + i) * 66 + row] * li;
        #pragma unroll
        for (int i = 0; i < 4; ++i) o1[i] = Oacc[(c8 * 8 + 4 + i) * 66 + row] * li;
        *(f4*)ob = o0;
        *(f4*)(ob + 4) = o1;
    }
}

// ---------------------------------------------------------------------------
extern "C" void kernel_launch(void* const* d_in, const int* in_sizes, int n_in,
                              void* d_out, int out_size, void* d_ws, size_t ws_size,
                              hipStream_t stream) {
    const float* q  = (const float*)d_in[0];
    const float* k  = (const float*)d_in[1];
    const float* v  = (const float*)d_in[2];
    // d_in[3] = causal mask (deterministic tril) — computed analytically
    const float* Wq = (const float*)d_in[4];
    const float* bq = (const float*)d_in[5];
    const float* Wk = (const float*)d_in[6];
    const float* bk = (const float*)d_in[7];
    const float* Wv = (const float*)d_in[8];
    const float* bv = (const float*)d_in[9];

    unsigned short* qp  = (unsigned short*)d_ws;           // [16384][64] bf16
    unsigned short* kp  = qp + (size_t)16384 * 64;
    unsigned short* vpT = kp + (size_t)16384 * 64;         // V^T tiles [b][t][d][key]

    ProjArgs pa;
    pa.X[0] = q;  pa.X[1] = k;  pa.X[2] = v;
    pa.W[0] = Wq; pa.W[1] = Wk; pa.W[2] = Wv;
    pa.b[0] = bq; pa.b[1] = bk; pa.b[2] = bv;
    pa.O[0] = qp; pa.O[1] = kp; pa.O[2] = vpT;
    proj_kernel<<<dim3(256, 3), 256, 0, stream>>>(pa);

    attn_kernel<<<dim3(32, 8), 512, 0, stream>>>(qp, kp, vpT, (float*)d_out);
}

// Round 12
// 78.673 us; speedup vs baseline: 1.1446x; 1.1446x over previous
//
#include <hip/hip_runtime.h>
#include <hip/hip_bf16.h>

typedef short s4 __attribute__((ext_vector_type(4)));
typedef short s8 __attribute__((ext_vector_type(8)));
typedef float f4 __attribute__((ext_vector_type(4)));

#define MFMA16(a, b, c) __builtin_amdgcn_mfma_f32_16x16x16bf16_1k(a, b, c, 0, 0, 0)

__device__ __forceinline__ short f2bf(float f) {
    union { float f; unsigned u; } v; v.f = f;
    unsigned r = v.u + 0x7fffu + ((v.u >> 16) & 1u);   // RNE
    return (short)(r >> 16);
}

// ---------------------------------------------------------------------------
// Kernel 1: projections — identical to round 8 (timed ~47 us warm).
// V (which==2) stored as transposed 64-key tiles vpT[b][tile][d][key].
// ---------------------------------------------------------------------------
struct ProjArgs {
    const float* X[3];
    const float* W[3];
    const float* b[3];
    unsigned short* O[3];
};

__global__ __launch_bounds__(256) void proj_kernel(ProjArgs args) {
    __shared__ short lA[64][68];   // [row][k]
    __shared__ short lW[64][68];   // [k][n]

    const int t  = threadIdx.x;
    const int wv = t >> 6, ln = t & 63, lg = ln >> 4, lr = ln & 15;
    const int which = blockIdx.y;

    const float* X = args.X[which] + (size_t)blockIdx.x * 64 * 1024;
    const float* W = args.W[which];

    f4 acc[4] = {f4{0,0,0,0}, f4{0,0,0,0}, f4{0,0,0,0}, f4{0,0,0,0}};

    for (int kk = 0; kk < 1024; kk += 64) {
        #pragma unroll
        for (int i = 0; i < 4; ++i) {
            int f  = t + i * 256;
            int r  = f >> 4;
            int c4 = f & 15;
            f4 a = *(const f4*)(X + (size_t)r * 1024 + kk + c4 * 4);
            f4 w = *(const f4*)(W + (size_t)(kk + r) * 64 + c4 * 4);
            s4 ab; ab[0]=f2bf(a[0]); ab[1]=f2bf(a[1]); ab[2]=f2bf(a[2]); ab[3]=f2bf(a[3]);
            s4 wb; wb[0]=f2bf(w[0]); wb[1]=f2bf(w[1]); wb[2]=f2bf(w[2]); wb[3]=f2bf(w[3]);
            *(s4*)&lA[r][c4 * 4] = ab;
            *(s4*)&lW[r][c4 * 4] = wb;
        }
        __syncthreads();

        #pragma unroll
        for (int ks = 0; ks < 4; ++ks) {
            s4 af = *(const s4*)&lA[wv * 16 + lr][ks * 16 + 4 * lg];
            #pragma unroll
            for (int nf = 0; nf < 4; ++nf) {
                s4 bf;
                #pragma unroll
                for (int e = 0; e < 4; ++e)
                    bf[e] = lW[ks * 16 + 4 * lg + e][nf * 16 + lr];
                acc[nf] = MFMA16(af, bf, acc[nf]);
            }
        }
        __syncthreads();
    }

    const float* bias = args.b[which];
    unsigned short* O = args.O[which];
    #pragma unroll
    for (int nf = 0; nf < 4; ++nf) {
        float bs = bias[nf * 16 + lr];
        int col = nf * 16 + lr;
        #pragma unroll
        for (int e = 0; e < 4; ++e) {
            int r = wv * 16 + 4 * lg + e;
            int grow = blockIdx.x * 64 + r;
            unsigned short val = (unsigned short)f2bf(acc[nf][e] + bs);
            if (which == 2) {
                size_t idx = (size_t)(grow >> 11) * 131072
                           + (size_t)((grow & 2047) >> 6) * 4096
                           + (size_t)col * 64 + (grow & 63);
                O[idx] = val;
            } else {
                O[(size_t)grow * 64 + col] = val;
            }
        }
    }
}

// ---------------------------------------------------------------------------
// Kernel 2 v12: flash-decoding split. Each (q-tile, batch) is processed by
// TWO blocks (z = KV chunk), each running the v8 structure (8 waves, 2-half
// split of its chunk, double-buffered LDS, 1 barrier/iter) on <=8 iters.
// KV tiles are partitioned (no extra traffic). Blocks dispatch big-qt first.
// Each block writes an unnormalized partial (m, l, O[q][d] f32) to ws;
// attn_merge combines. grid (64, 8) = 512 blocks -> 2 blocks/CU.
// ---------------------------------------------------------------------------
__global__ __launch_bounds__(512) void attn_part(const unsigned short* __restrict__ qp,
                                                 const unsigned short* __restrict__ kp,
                                                 const unsigned short* __restrict__ vpT,
                                                 float* __restrict__ partO,
                                                 float* __restrict__ partML) {
    __shared__ short lK[2][2][64][72];   // [half][buf][key][d]
    __shared__ short lV[2][2][64][72];   // [half][buf][d][key]

    const int t    = threadIdx.x;
    const int wave = t >> 6, ln = t & 63, lg = ln >> 4, lr = ln & 15;
    const int half = wave >> 2, hw = wave & 3;
    const int b = blockIdx.y, x = blockIdx.x;
    const int qt = 31 - (x >> 1), z = x & 1;      // big qt dispatches first
    const int P = qt + 1;
    const int c = (P + 1) >> 1;                   // chunk-0 size
    const int base  = z ? c : 0;
    const int chunk = z ? (P - c) : c;
    const int hA = (chunk + 1) >> 1;              // iterations (0 if empty)
    const int qrow = qt * 64 + hw * 16 + lr;

    // staging role: 128-thr groups g: 0=K halfA, 1=V halfA, 2=K halfB, 3=V halfB
    const int g = t >> 7, gi = t & 127, ghalf = g >> 1;
    const bool isV = (g & 1) != 0;
    const unsigned short* tb = (isV ? vpT : kp) + (size_t)b * 131072;

    const unsigned short* qpb = qp + (size_t)b * 131072;
    s4 qf[4];
    #pragma unroll
    for (int ks = 0; ks < 4; ++ks)
        qf[ks] = *(const s4*)(qpb + (size_t)qrow * 64 + ks * 16 + 4 * lg);

    f4 accO[4] = {f4{0,0,0,0}, f4{0,0,0,0}, f4{0,0,0,0}, f4{0,0,0,0}};
    float m = -3e38f, lsum = 0.f;

    // prologue prefetch (valid memory even when hA==0; loop then skips)
    s8 stg[4];
    {
        const unsigned short* p = tb + (size_t)(base + (ghalf ? hA : 0)) * 4096;
        #pragma unroll
        for (int i = 0; i < 4; ++i)
            stg[i] = *(const s8*)(p + (gi + 128 * i) * 8);
    }

    int buf = 0;
    for (int j = 0; j < hA; ++j) {
        {
            short (*dst)[72] = isV ? lV[ghalf][buf] : lK[ghalf][buf];
            #pragma unroll
            for (int i = 0; i < 4; ++i) {
                int s = gi + 128 * i;
                *(s8*)&dst[s >> 3][(s & 7) * 8] = stg[i];
            }
        }
        __syncthreads();

        if (j + 1 < hA) {
            const unsigned short* p = tb + (size_t)(base + (ghalf ? hA : 0) + j + 1) * 4096;
            #pragma unroll
            for (int i = 0; i < 4; ++i)
                stg[i] = *(const s8*)(p + (gi + 128 * i) * 8);
        }

        const int kt = base + (half ? hA : 0) + j;
        if (kt < base + chunk) {                 // half-B pad iters skip
            f4 st[4];
            #pragma unroll
            for (int kf = 0; kf < 4; ++kf) {
                f4 a = f4{0,0,0,0};
                #pragma unroll
                for (int ks = 0; ks < 4; ++ks) {
                    s4 kfr = *(const s4*)&lK[half][buf][kf * 16 + lr][ks * 16 + 4 * lg];
                    a = MFMA16(kfr, qf[ks], a);
                }
                st[kf] = a;
            }

            const bool diag = (kt == qt);
            const int kbase = kt * 64;
            float smax = -3e38f;
            #pragma unroll
            for (int kf = 0; kf < 4; ++kf) {
                #pragma unroll
                for (int e = 0; e < 4; ++e) {
                    float s = st[kf][e] * 0.125f;
                    if (diag && (kbase + kf * 16 + 4 * lg + e > qrow)) s = -3e38f;
                    st[kf][e] = s;
                    smax = fmaxf(smax, s);
                }
            }
            smax = fmaxf(smax, __shfl_xor(smax, 16));
            smax = fmaxf(smax, __shfl_xor(smax, 32));

            float mnew  = fmaxf(m, smax);
            float scale = __expf(m - mnew);
            float psum  = 0.f;
            s4 pf[4];
            #pragma unroll
            for (int kf = 0; kf < 4; ++kf) {
                f4 p;
                #pragma unroll
                for (int e = 0; e < 4; ++e) { p[e] = __expf(st[kf][e] - mnew); psum += p[e]; }
                s4 pb; pb[0]=f2bf(p[0]); pb[1]=f2bf(p[1]); pb[2]=f2bf(p[2]); pb[3]=f2bf(p[3]);
                pf[kf] = pb;
            }
            psum += __shfl_xor(psum, 16);
            psum += __shfl_xor(psum, 32);
            lsum = lsum * scale + psum;
            m = mnew;
            #pragma unroll
            for (int df = 0; df < 4; ++df) accO[df] *= scale;

            #pragma unroll
            for (int df = 0; df < 4; ++df) {
                #pragma unroll
                for (int kf = 0; kf < 4; ++kf) {
                    s4 vf = *(const s4*)&lV[half][buf][df * 16 + lr][kf * 16 + 4 * lg];
                    accO[df] = MFMA16(vf, pf[kf], accO[df]);
                }
            }
        }
        buf ^= 1;
    }

    // ---- internal 2-half merge, then write partial (unnormalized) ----
    __syncthreads();
    float* ex = (float*)&lK[0][0][0][0];     // 256*19 floats = 19.4 KB
    const int idx = (hw * 64 + ln) * 19;
    if (half == 1) {
        ex[idx + 0] = m;
        ex[idx + 1] = lsum;
        #pragma unroll
        for (int df = 0; df < 4; ++df)
            #pragma unroll
            for (int e = 0; e < 4; ++e)
                ex[idx + 2 + df * 4 + e] = accO[df][e];
    }
    __syncthreads();
    if (half == 0) {
        float mB = ex[idx + 0], lB = ex[idx + 1];
        float mx = fmaxf(m, mB);
        float sA = __expf(m - mx), sB = __expf(mB - mx);
        float lP = lsum * sA + lB * sB;

        const size_t pidx = ((size_t)b * 32 + qt) * 2 + z;
        float* Od = partO + pidx * 4096;         // [q][d] fp32
        const int q = hw * 16 + lr;
        #pragma unroll
        for (int df = 0; df < 4; ++df) {
            f4 o;
            #pragma unroll
            for (int e = 0; e < 4; ++e)
                o[e] = accO[df][e] * sA + ex[idx + 2 + df * 4 + e] * sB;
            *(f4*)(Od + (size_t)q * 64 + df * 16 + 4 * lg) = o;
        }
        if (lg == 0) {
            partML[pidx * 128 + q * 2 + 0] = mx;
            partML[pidx * 128 + q * 2 + 1] = lP;
        }
    }
}

// ---------------------------------------------------------------------------
// Kernel 3: merge the two KV-chunk partials. grid (32, 8), 256 thr.
// Thread t: q = t>>2, d-range = (t&3)*16..+15. Fully f4-coalesced.
// ---------------------------------------------------------------------------
__global__ __launch_bounds__(256) void attn_merge(const float* __restrict__ partO,
                                                  const float* __restrict__ partML,
                                                  float* __restrict__ out) {
    const int t = threadIdx.x;
    const int g = blockIdx.x, b = blockIdx.y;
    const int q = t >> 2, dq = t & 3;

    const size_t p0 = ((size_t)b * 32 + g) * 2;
    const size_t p1 = p0 + 1;
    float m0 = partML[p0 * 128 + q * 2], l0 = partML[p0 * 128 + q * 2 + 1];
    float m1 = partML[p1 * 128 + q * 2], l1 = partML[p1 * 128 + q * 2 + 1];
    float M  = fmaxf(m0, m1);
    float s0 = __expf(m0 - M), s1 = __expf(m1 - M);
    float inv = 1.f / (l0 * s0 + l1 * s1);

    const float* O0 = partO + p0 * 4096 + (size_t)q * 64 + dq * 16;
    const float* O1 = partO + p1 * 4096 + (size_t)q * 64 + dq * 16;
    float* ob = out + ((size_t)b * 2048 + g * 64 + q) * 64 + dq * 16;
    #pragma unroll
    for (int i = 0; i < 4; ++i) {
        f4 a = *(const f4*)(O0 + 4 * i);
        f4 c = *(const f4*)(O1 + 4 * i);
        f4 o;
        #pragma unroll
        for (int e = 0; e < 4; ++e) o[e] = (a[e] * s0 + c[e] * s1) * inv;
        *(f4*)(ob + 4 * i) = o;
    }
}

// ---------------------------------------------------------------------------
extern "C" void kernel_launch(void* const* d_in, const int* in_sizes, int n_in,
                              void* d_out, int out_size, void* d_ws, size_t ws_size,
                              hipStream_t stream) {
    const float* q  = (const float*)d_in[0];
    const float* k  = (const float*)d_in[1];
    const float* v  = (const float*)d_in[2];
    // d_in[3] = causal mask (deterministic tril) — computed analytically
    const float* Wq = (const float*)d_in[4];
    const float* bq = (const float*)d_in[5];
    const float* Wk = (const float*)d_in[6];
    const float* bk = (const float*)d_in[7];
    const float* Wv = (const float*)d_in[8];
    const float* bv = (const float*)d_in[9];

    unsigned short* qp  = (unsigned short*)d_ws;           // [16384][64] bf16
    unsigned short* kp  = qp + (size_t)16384 * 64;
    unsigned short* vpT = kp + (size_t)16384 * 64;         // V^T tiles [b][t][d][key]
    float* partO  = (float*)(vpT + (size_t)16384 * 64);    // [512][64][64] f32 (8 MB)
    float* partML = partO + (size_t)512 * 4096;            // [512][64][2] f32 (256 KB)

    ProjArgs pa;
    pa.X[0] = q;  pa.X[1] = k;  pa.X[2] = v;
    pa.W[0] = Wq; pa.W[1] = Wk; pa.W[2] = Wv;
    pa.b[0] = bq; pa.b[1] = bk; pa.b[2] = bv;
    pa.O[0] = qp; pa.O[1] = kp; pa.O[2] = vpT;
    proj_kernel<<<dim3(256, 3), 256, 0, stream>>>(pa);

    attn_part<<<dim3(64, 8), 512, 0, stream>>>(qp, kp, vpT, partO, partML);
    attn_merge<<<dim3(32, 8), 256, 0, stream>>>(partO, partML, (float*)d_out);
}